// Round 1
// baseline (120.197 us; speedup 1.0000x reference)
//
#include <hip/hip_runtime.h>
#include <hip/hip_bf16.h>

// =====================================================================
// VeroneseDecoding: out[:, 0:4] = top-eigenvector(sym4x4(z[:, :10])) (sign-fixed)
//                   out[:, 4:132] = relu(z @ W1 + b1) @ W2 + b2
// Inputs (f32): z[65536,256], W1[256,1024], b1[1024], W2[1024,128], b2[128]
// Output (f32): [65536,132]
// =====================================================================

typedef short s16x8 __attribute__((ext_vector_type(8)));   // 8 bf16 (4 VGPRs)
typedef float f32x4 __attribute__((ext_vector_type(4)));

__device__ __forceinline__ f32x4 mfma16(s16x8 a, s16x8 b, f32x4 c) {
    return __builtin_amdgcn_mfma_f32_16x16x32_bf16(a, b, c, 0, 0, 0);
}

// manual RNE f32 -> bf16 bits (finite values only)
__device__ __forceinline__ short f2bf(float f) {
    unsigned int u = __float_as_uint(f);
    u = (u + 0x7fffu + ((u >> 16) & 1u)) >> 16;
    return (short)u;
}

// ---------------------------------------------------------------------
// prep: W1^T and W2^T -> bf16, XOR-swizzled in 16B units, into d_ws.
// w1t: [n1=1024 rows][32 units]; unit (u ^ (n1&7)) holds W1[u*8 .. u*8+7][n1]
// w2t: [n2= 128 rows][128 units]; unit (U ^ (n2&7)) holds W2[U*8 .. U*8+7][n2]
// (swizzle flips only low 3 bits of the unit index -> stays inside each
//  128-col chunk slice, so chunk staging remains a plain linear copy)
// ---------------------------------------------------------------------
__global__ __launch_bounds__(256) void prep_weights(
    const float* __restrict__ W1, const float* __restrict__ W2,
    uint4* __restrict__ w1t, uint4* __restrict__ w2t)
{
    int tid = blockIdx.x * 256 + threadIdx.x;
    union { short b[8]; uint4 v; } pk;
    if (tid < 32768) {                 // 32 units * 1024 cols
        int u  = tid >> 10;            // 0..31 (k-unit)
        int n1 = tid & 1023;           // 0..1023
        #pragma unroll
        for (int j = 0; j < 8; ++j)
            pk.b[j] = f2bf(W1[(u * 8 + j) * 1024 + n1]);
        w1t[n1 * 32 + (u ^ (n1 & 7))] = pk.v;
    } else {                           // 128 units * 128 cols
        int id = tid - 32768;
        int U  = id >> 7;              // 0..127 (k2-unit)
        int n2 = id & 127;             // 0..127
        #pragma unroll
        for (int j = 0; j < 8; ++j)
            pk.b[j] = f2bf(W2[(U * 8 + j) * 128 + n2]);
        w2t[n2 * 128 + (U ^ (n2 & 7))] = pk.v;
    }
}

// ---------------------------------------------------------------------
// eig4: per-row 4x4 symmetric Jacobi eigensolver, pick largest eigenvalue,
// sign-normalize like the reference: q *= sign(q[0] + 1e-9)
// ---------------------------------------------------------------------
__global__ __launch_bounds__(256) void eig4_kernel(const float* __restrict__ z,
                                                   float* __restrict__ out)
{
    int row = blockIdx.x * 256 + threadIdx.x;
    const float* zr = z + (size_t)row * 256;
    float z0 = zr[0], z1 = zr[1], z2 = zr[2], z3 = zr[3], z4 = zr[4];
    float z5 = zr[5], z6 = zr[6], z7 = zr[7], z8 = zr[8], z9 = zr[9];

    // triu fill: (0,0)z0 (0,1)z1 (0,2)z2 (0,3)z3 (1,1)z4 (1,2)z5 (1,3)z6
    //            (2,2)z7 (2,3)z8 (3,3)z9, mirrored
    float A[4][4] = {{z0, z1, z2, z3},
                     {z1, z4, z5, z6},
                     {z2, z5, z7, z8},
                     {z3, z6, z8, z9}};
    float V[4][4] = {{1.f, 0.f, 0.f, 0.f},
                     {0.f, 1.f, 0.f, 0.f},
                     {0.f, 0.f, 1.f, 0.f},
                     {0.f, 0.f, 0.f, 1.f}};

#define ROT(p, qq) do {                                                   \
        float apq = A[p][qq];                                             \
        if (fabsf(apq) > 1e-30f) {                                        \
            float tau = (A[qq][qq] - A[p][p]) / (2.0f * apq);             \
            float tt  = copysignf(1.0f, tau) /                            \
                        (fabsf(tau) + sqrtf(1.0f + tau * tau));           \
            float cth = 1.0f / sqrtf(1.0f + tt * tt);                     \
            float sth = tt * cth;                                         \
            _Pragma("unroll")                                             \
            for (int k = 0; k < 4; ++k) {                                 \
                float akp = A[k][p], akq = A[k][qq];                      \
                A[k][p]  = cth * akp - sth * akq;                         \
                A[k][qq] = sth * akp + cth * akq;                         \
            }                                                             \
            _Pragma("unroll")                                             \
            for (int k = 0; k < 4; ++k) {                                 \
                float apk = A[p][k], aqk = A[qq][k];                      \
                A[p][k]  = cth * apk - sth * aqk;                         \
                A[qq][k] = sth * apk + cth * aqk;                         \
            }                                                             \
            _Pragma("unroll")                                             \
            for (int k = 0; k < 4; ++k) {                                 \
                float vkp = V[k][p], vkq = V[k][qq];                      \
                V[k][p]  = cth * vkp - sth * vkq;                         \
                V[k][qq] = sth * vkp + cth * vkq;                         \
            }                                                             \
        }                                                                 \
    } while (0)

    for (int sweep = 0; sweep < 10; ++sweep) {
        ROT(0, 1); ROT(0, 2); ROT(0, 3); ROT(1, 2); ROT(1, 3); ROT(2, 3);
    }
#undef ROT

    // branchless argmax over diagonal (keep everything in registers)
    float bv = A[0][0];
    float q0 = V[0][0], q1 = V[1][0], q2 = V[2][0], q3 = V[3][0];
    #pragma unroll
    for (int k = 1; k < 4; ++k) {
        bool better = A[k][k] > bv;
        bv = better ? A[k][k] : bv;
        q0 = better ? V[0][k] : q0;
        q1 = better ? V[1][k] : q1;
        q2 = better ? V[2][k] : q2;
        q3 = better ? V[3][k] : q3;
    }
    float sgn = (q0 + 1e-9f) >= 0.0f ? 1.0f : -1.0f;
    float* op = out + (size_t)row * 132;
    op[0] = sgn * q0; op[1] = sgn * q1; op[2] = sgn * q2; op[3] = sgn * q3;
}

// ---------------------------------------------------------------------
// fused MLP: BM=256 rows/block, 512 threads = 8 waves x 32 rows.
// K1=256 (z frags persistent in registers), N1=1024 processed in 8 chunks
// of 128; each chunk: GEMM1 -> relu+bias -> h to LDS (bf16, swizzled,
// intra-wave only) -> GEMM2 partial accumulate over k2-chunk.
// LDS: bs1 64KB (W1^T chunk) | hs 64KB (h) | bs2 32KB (W2^T chunk) = 160KB
// ---------------------------------------------------------------------
__global__ __launch_bounds__(512) void fused_mlp(
    const float* __restrict__ z, const float* __restrict__ b1,
    const float* __restrict__ b2, const uint4* __restrict__ w1t,
    const uint4* __restrict__ w2t, float* __restrict__ out)
{
    __shared__ __align__(16) unsigned char lds[163840];
    unsigned char* bs1 = lds;            // [128 n1][512B]  (32 16B-units/row)
    unsigned char* hs  = lds + 65536;    // [256 m ][256B]  (16 units/row)
    unsigned char* bs2 = lds + 131072;   // [128 n2][256B]  (16 units/row)

    const int t    = threadIdx.x;
    const int lane = t & 63;
    const int w    = t >> 6;        // wave 0..7
    const int q    = lane >> 4;     // 0..3
    const int r16  = lane & 15;
    const int bm0  = blockIdx.x * 256;
    const int rowbase = bm0 + w * 32;

    const f32x4 zero4 = {0.f, 0.f, 0.f, 0.f};

    // ---- persistent z A-fragments: zf[mr][s] = z[rowbase+16mr+r16][32s+8q .. +8)
    s16x8 zf[2][8];
    #pragma unroll
    for (int mr = 0; mr < 2; ++mr) {
        const float* zp = z + (size_t)(rowbase + mr * 16 + r16) * 256;
        #pragma unroll
        for (int s = 0; s < 8; ++s) {
            const float4* p = (const float4*)(zp + s * 32 + q * 8);
            float4 v0 = p[0], v1 = p[1];
            s16x8 a;
            a[0] = f2bf(v0.x); a[1] = f2bf(v0.y); a[2] = f2bf(v0.z); a[3] = f2bf(v0.w);
            a[4] = f2bf(v1.x); a[5] = f2bf(v1.y); a[6] = f2bf(v1.z); a[7] = f2bf(v1.w);
            zf[mr][s] = a;
        }
    }

    f32x4 acc2[2][8];
    #pragma unroll
    for (int mr = 0; mr < 2; ++mr)
        #pragma unroll
        for (int n = 0; n < 8; ++n) acc2[mr][n] = zero4;

    for (int c = 0; c < 8; ++c) {
        __syncthreads();   // previous chunk's LDS reads complete before overwrite

        // stage W1^T chunk (64KB) — pre-swizzled in ws, linear copy
        {
            const uint4* src = w1t + c * 4096;
            #pragma unroll
            for (int i = 0; i < 8; ++i) {
                int u = t + i * 512;
                *(uint4*)(bs1 + u * 16) = src[u];
            }
            // stage W2^T chunk (32KB): row n2 -> 16 units from its c-slice
            #pragma unroll
            for (int i = 0; i < 4; ++i) {
                int gid = t + i * 512;
                int n2 = gid >> 4, sl = gid & 15;
                *(uint4*)(bs2 + gid * 16) = w2t[n2 * 128 + c * 16 + sl];
            }
        }
        __syncthreads();

        // ---- GEMM1 (+bias+relu+h-write), one 16-col tile at a time ----
        #pragma unroll
        for (int ct = 0; ct < 8; ++ct) {
            f32x4 a0 = zero4, a1 = zero4;
            const int n1 = ct * 16 + r16;            // local col in chunk
            #pragma unroll
            for (int s = 0; s < 8; ++s) {
                int up = (s * 4 + q) ^ (n1 & 7);
                s16x8 bfr = *(const s16x8*)(bs1 + n1 * 512 + up * 16);
                a0 = mfma16(zf[0][s], bfr, a0);
                a1 = mfma16(zf[1][s], bfr, a1);
            }
            const float bv = b1[c * 128 + ct * 16 + r16];
            const int k2 = ct * 16 + r16;            // h column == GEMM2 k
            const int uk = k2 >> 3;
            #pragma unroll
            for (int mr = 0; mr < 2; ++mr) {
                f32x4 av = (mr == 0) ? a0 : a1;
                #pragma unroll
                for (int r = 0; r < 4; ++r) {
                    int m = w * 32 + mr * 16 + q * 4 + r;
                    float hv = fmaxf(av[r] + bv, 0.f);
                    int up = uk ^ (m & 7);
                    *(short*)(hs + m * 256 + up * 16 + (k2 & 7) * 2) = f2bf(hv);
                }
            }
        }

        // ---- GEMM2 partial: out += h_chunk @ W2_chunk ----
        // hs rows [32w,32w+32) written and read only by wave w -> no barrier
        #pragma unroll
        for (int s2 = 0; s2 < 4; ++s2) {
            s16x8 af[2];
            #pragma unroll
            for (int mr = 0; mr < 2; ++mr) {
                int m = w * 32 + mr * 16 + r16;
                int up = (s2 * 4 + q) ^ (m & 7);
                af[mr] = *(const s16x8*)(hs + m * 256 + up * 16);
            }
            #pragma unroll
            for (int ct2 = 0; ct2 < 8; ++ct2) {
                int n2 = ct2 * 16 + r16;
                int up = (s2 * 4 + q) ^ (n2 & 7);
                s16x8 bfr = *(const s16x8*)(bs2 + n2 * 256 + up * 16);
                acc2[0][ct2] = mfma16(af[0], bfr, acc2[0][ct2]);
                acc2[1][ct2] = mfma16(af[1], bfr, acc2[1][ct2]);
            }
        }
    }

    // ---- epilogue: out[:, 4 + n2] = acc2 + b2 ----
    #pragma unroll
    for (int ct2 = 0; ct2 < 8; ++ct2) {
        const float b2v = b2[ct2 * 16 + r16];
        #pragma unroll
        for (int mr = 0; mr < 2; ++mr) {
            #pragma unroll
            for (int r = 0; r < 4; ++r) {
                int m = w * 32 + mr * 16 + q * 4 + r;
                out[(size_t)(bm0 + m) * 132 + 4 + ct2 * 16 + r16] =
                    acc2[mr][ct2][r] + b2v;
            }
        }
    }
}

// ---------------------------------------------------------------------
extern "C" void kernel_launch(void* const* d_in, const int* in_sizes, int n_in,
                              void* d_out, int out_size, void* d_ws, size_t ws_size,
                              hipStream_t stream) {
    const float* z  = (const float*)d_in[0];
    const float* W1 = (const float*)d_in[1];
    const float* b1 = (const float*)d_in[2];
    const float* W2 = (const float*)d_in[3];
    const float* b2 = (const float*)d_in[4];
    float* out = (float*)d_out;

    // ws layout: [0, 512KB) W1^T bf16 swizzled, [512KB, 768KB) W2^T bf16 swizzled
    uint4* w1t = (uint4*)d_ws;
    uint4* w2t = (uint4*)((char*)d_ws + 512 * 1024);
    // requires ws_size >= 786432 bytes

    hipLaunchKernelGGL(prep_weights, dim3(192), dim3(256), 0, stream,
                       W1, W2, w1t, w2t);
    hipLaunchKernelGGL(eig4_kernel, dim3(256), dim3(256), 0, stream, z, out);
    hipLaunchKernelGGL(fused_mlp, dim3(256), dim3(512), 0, stream,
                       z, b1, b2, (const uint4*)w1t, (const uint4*)w2t, out);
}

// Round 2
// 100.804 us; speedup vs baseline: 1.1924x; 1.1924x over previous
//
#include <hip/hip_runtime.h>
#include <hip/hip_bf16.h>

// =====================================================================
// VeroneseDecoding: out[:, 0:4] = top-eigenvector(sym4x4(z[:, :10])) (sign-fixed)
//                   out[:, 4:132] = relu(z @ W1 + b1) @ W2 + b2
// Inputs (f32): z[65536,256], W1[256,1024], b1[1024], W2[1024,128], b2[128]
// Output (f32): [65536,132]
// =====================================================================

typedef short s16x8 __attribute__((ext_vector_type(8)));   // 8 bf16 (4 VGPRs)
typedef float f32x4 __attribute__((ext_vector_type(4)));

__device__ __forceinline__ f32x4 mfma16(s16x8 a, s16x8 b, f32x4 c) {
    return __builtin_amdgcn_mfma_f32_16x16x32_bf16(a, b, c, 0, 0, 0);
}

// manual RNE f32 -> bf16 bits (finite values only)
__device__ __forceinline__ short f2bf(float f) {
    unsigned int u = __float_as_uint(f);
    u = (u + 0x7fffu + ((u >> 16) & 1u)) >> 16;
    return (short)u;
}

// async global->LDS, 16B per lane. Dest must be wave-uniform base + lane*16.
__device__ __forceinline__ void gload_lds16(const void* g, void* l) {
    __builtin_amdgcn_global_load_lds(
        (const __attribute__((address_space(1))) unsigned int*)g,
        (__attribute__((address_space(3))) unsigned int*)l, 16, 0, 0);
}

// ---------------------------------------------------------------------
// prep: W1^T and W2^T -> bf16, XOR-swizzled in 16B units, into d_ws.
// w1t: [1024 n1][32 units]; unit (u ^ (n1&7)) holds W1[u*8 .. u*8+8)[n1]
// w2t: [ 128 n2][128 units]; unit (U ^ (n2&7)) holds W2[U*8 .. U*8+8)[n2]
// (swizzle flips only low 3 unit bits -> stays inside each 64-col k-slice,
//  so per-chunk staging is a plain linear copy)
// ---------------------------------------------------------------------
__global__ __launch_bounds__(256) void prep_weights(
    const float* __restrict__ W1, const float* __restrict__ W2,
    uint4* __restrict__ w1t, uint4* __restrict__ w2t)
{
    int tid = blockIdx.x * 256 + threadIdx.x;
    union { short b[8]; uint4 v; } pk;
    if (tid < 32768) {                 // 32 units * 1024 cols
        int u  = tid >> 10;            // k-unit 0..31
        int n1 = tid & 1023;
        #pragma unroll
        for (int j = 0; j < 8; ++j)
            pk.b[j] = f2bf(W1[(u * 8 + j) * 1024 + n1]);
        w1t[n1 * 32 + (u ^ (n1 & 7))] = pk.v;
    } else {                           // 128 units * 128 cols
        int id = tid - 32768;
        int U  = id >> 7;              // k-unit 0..127
        int n2 = id & 127;
        #pragma unroll
        for (int j = 0; j < 8; ++j)
            pk.b[j] = f2bf(W2[(U * 8 + j) * 128 + n2]);
        w2t[n2 * 128 + (U ^ (n2 & 7))] = pk.v;
    }
}

// ---------------------------------------------------------------------
// fused kernel: BM=128 rows/block, 256 threads = 4 waves x 32 rows.
// grid 512 -> 2 blocks/CU (LDS 64KB).
//  - eig: Jacobi 4x4 per row (lanes 0..31 of each wave)
//  - GEMM1 (swapped: A=W1^T from LDS, B=z from regs) -> h^T in D
//    -> packed b64 h-write (relu+bias) into per-wave LDS, swizzled
//  - GEMM2 (A=h from LDS b128, B=W2^T from LDS) accumulate over 16 chunks
// LDS: bs1 32KB (W1^T 64-col chunk) | hs 16KB (4x4KB per-wave h) | bs2 16KB
// ---------------------------------------------------------------------
__global__ __launch_bounds__(256, 2) void fused_all(
    const float* __restrict__ z, const float* __restrict__ b1,
    const float* __restrict__ b2, const uint4* __restrict__ w1t,
    const uint4* __restrict__ w2t, float* __restrict__ out)
{
    __shared__ __align__(16) unsigned char lds[65536];
    unsigned char* bs1 = lds;            // [64 n1][512B]
    unsigned char* hs  = lds + 32768;    // 4 waves x [32 m][128B]
    unsigned char* bs2 = lds + 49152;    // [128 n2][128B]

    const int t    = threadIdx.x;
    const int lane = t & 63;
    const int w    = t >> 6;        // wave 0..3
    const int q    = lane >> 4;     // 0..3
    const int r16  = lane & 15;
    const int bm0  = blockIdx.x * 128;
    const int rowbase = bm0 + w * 32;

    // ================= eig (lanes 0..31 handle the wave's 32 rows) =====
    if (lane < 32) {
        int row = rowbase + lane;
        const float4* zr4 = (const float4*)(z + (size_t)row * 256);
        float4 v0 = zr4[0], v1 = zr4[1], v2 = zr4[2];
        float z0 = v0.x, z1 = v0.y, z2 = v0.z, z3 = v0.w;
        float z4 = v1.x, z5 = v1.y, z6 = v1.z, z7 = v1.w;
        float z8 = v2.x, z9 = v2.y;

        float A[4][4] = {{z0, z1, z2, z3},
                         {z1, z4, z5, z6},
                         {z2, z5, z7, z8},
                         {z3, z6, z8, z9}};
        float V[4][4] = {{1.f, 0.f, 0.f, 0.f},
                         {0.f, 1.f, 0.f, 0.f},
                         {0.f, 0.f, 1.f, 0.f},
                         {0.f, 0.f, 0.f, 1.f}};

#define ROT(p, qq) do {                                                   \
        float apq = A[p][qq];                                             \
        if (fabsf(apq) > 1e-30f) {                                        \
            float tau = (A[qq][qq] - A[p][p]) / (2.0f * apq);             \
            float tt  = copysignf(1.0f, tau) /                            \
                        (fabsf(tau) + sqrtf(1.0f + tau * tau));           \
            float cth = 1.0f / sqrtf(1.0f + tt * tt);                     \
            float sth = tt * cth;                                         \
            _Pragma("unroll")                                             \
            for (int k = 0; k < 4; ++k) {                                 \
                float akp = A[k][p], akq = A[k][qq];                      \
                A[k][p]  = cth * akp - sth * akq;                         \
                A[k][qq] = sth * akp + cth * akq;                         \
            }                                                             \
            _Pragma("unroll")                                             \
            for (int k = 0; k < 4; ++k) {                                 \
                float apk = A[p][k], aqk = A[qq][k];                      \
                A[p][k]  = cth * apk - sth * aqk;                         \
                A[qq][k] = sth * apk + cth * aqk;                         \
            }                                                             \
            _Pragma("unroll")                                             \
            for (int k = 0; k < 4; ++k) {                                 \
                float vkp = V[k][p], vkq = V[k][qq];                      \
                V[k][p]  = cth * vkp - sth * vkq;                         \
                V[k][qq] = sth * vkp + cth * vkq;                         \
            }                                                             \
        }                                                                 \
    } while (0)

        for (int sweep = 0; sweep < 10; ++sweep) {
            ROT(0, 1); ROT(0, 2); ROT(0, 3); ROT(1, 2); ROT(1, 3); ROT(2, 3);
        }
#undef ROT

        float bv = A[0][0];
        float q0 = V[0][0], q1 = V[1][0], q2 = V[2][0], q3 = V[3][0];
        #pragma unroll
        for (int k = 1; k < 4; ++k) {
            bool better = A[k][k] > bv;
            bv = better ? A[k][k] : bv;
            q0 = better ? V[0][k] : q0;
            q1 = better ? V[1][k] : q1;
            q2 = better ? V[2][k] : q2;
            q3 = better ? V[3][k] : q3;
        }
        float sgn = (q0 + 1e-9f) >= 0.0f ? 1.0f : -1.0f;
        float* op = out + (size_t)row * 132;
        op[0] = sgn * q0; op[1] = sgn * q1; op[2] = sgn * q2; op[3] = sgn * q3;
    }

    // ================= persistent z B-fragments =========================
    // zf[mr][s] = z[rowbase + mr*16 + r16][s*32 + q*8 .. +8)  (B-frag layout)
    const f32x4 zero4 = {0.f, 0.f, 0.f, 0.f};
    s16x8 zf[2][8];
    #pragma unroll
    for (int mr = 0; mr < 2; ++mr) {
        const float* zp = z + (size_t)(rowbase + mr * 16 + r16) * 256;
        #pragma unroll
        for (int s = 0; s < 8; ++s) {
            const float4* p = (const float4*)(zp + s * 32 + q * 8);
            float4 v0 = p[0], v1 = p[1];
            s16x8 a;
            a[0] = f2bf(v0.x); a[1] = f2bf(v0.y); a[2] = f2bf(v0.z); a[3] = f2bf(v0.w);
            a[4] = f2bf(v1.x); a[5] = f2bf(v1.y); a[6] = f2bf(v1.z); a[7] = f2bf(v1.w);
            zf[mr][s] = a;
        }
    }

    f32x4 acc2[2][8];
    #pragma unroll
    for (int mr = 0; mr < 2; ++mr)
        #pragma unroll
        for (int n = 0; n < 8; ++n) acc2[mr][n] = zero4;

    unsigned char* hw = hs + w * 4096;   // wave-private h: [32 m][8 u][16B]

    for (int c = 0; c < 16; ++c) {       // 16 chunks of 64 n1-cols
        __syncthreads();                 // prev chunk's bs1/bs2 reads done

        // ---- stage W1^T chunk (32KB) + W2^T chunk (16KB), async -------
        const uint4* s1 = w1t + c * 2048;
        #pragma unroll
        for (int i = 0; i < 8; ++i) {
            int f = i * 256 + t;
            gload_lds16(s1 + f, bs1 + f * 16);
        }
        #pragma unroll
        for (int i = 0; i < 4; ++i) {
            int f = i * 256 + t;         // f = n2*8 + u
            gload_lds16(w2t + (f >> 3) * 128 + c * 8 + (f & 7), bs2 + f * 16);
        }
        __syncthreads();                 // staging complete

        // ---- GEMM1 (swapped): D[n1][m] = sum_k W1^T[n1][k] * z^T[k][m] ----
        #pragma unroll
        for (int ct = 0; ct < 4; ++ct) {
            f32x4 a0 = zero4, a1 = zero4;
            const int n1 = ct * 16 + r16;
            #pragma unroll
            for (int s = 0; s < 8; ++s) {
                int u = (s * 4 + q) ^ (r16 & 7);
                s16x8 afr = *(const s16x8*)(bs1 + n1 * 512 + u * 16);
                a0 = mfma16(afr, zf[0][s], a0);
                a1 = mfma16(afr, zf[1][s], a1);
            }
            // lane holds h[m][k2] for k2 = ct*16 + q*4 + r (r=0..3),
            // m = mr*16 + r16. relu+bias, pack 4 bf16, one b64 write.
            float4 bv = *(const float4*)(b1 + c * 64 + ct * 16 + q * 4);
            #pragma unroll
            for (int mr = 0; mr < 2; ++mr) {
                f32x4 av = mr ? a1 : a0;
                union { short h[4]; unsigned long long v; } pk;
                pk.h[0] = f2bf(fmaxf(av[0] + bv.x, 0.f));
                pk.h[1] = f2bf(fmaxf(av[1] + bv.y, 0.f));
                pk.h[2] = f2bf(fmaxf(av[2] + bv.z, 0.f));
                pk.h[3] = f2bf(fmaxf(av[3] + bv.w, 0.f));
                int m = mr * 16 + r16;
                int u = (2 * ct + (q >> 1)) ^ (m & 7);
                *(unsigned long long*)(hw + m * 128 + u * 16 + (q & 1) * 8) = pk.v;
            }
        }

        // ---- GEMM2 partial: out += h_chunk @ W2_chunk (k2-range 64) ----
        #pragma unroll
        for (int s2 = 0; s2 < 2; ++s2) {
            s16x8 af[2];
            #pragma unroll
            for (int mr = 0; mr < 2; ++mr) {
                int m = mr * 16 + r16;
                int u = (s2 * 4 + q) ^ (m & 7);
                af[mr] = *(const s16x8*)(hw + m * 128 + u * 16);
            }
            #pragma unroll
            for (int ct2 = 0; ct2 < 8; ++ct2) {
                int n2 = ct2 * 16 + r16;
                int u = (s2 * 4 + q) ^ (n2 & 7);
                s16x8 bfr = *(const s16x8*)(bs2 + n2 * 128 + u * 16);
                acc2[0][ct2] = mfma16(af[0], bfr, acc2[0][ct2]);
                acc2[1][ct2] = mfma16(af[1], bfr, acc2[1][ct2]);
            }
        }
    }

    // ---- epilogue: out[:, 4 + n2] = acc2 + b2 ----
    #pragma unroll
    for (int ct2 = 0; ct2 < 8; ++ct2) {
        const float b2v = b2[ct2 * 16 + r16];
        #pragma unroll
        for (int mr = 0; mr < 2; ++mr) {
            #pragma unroll
            for (int r = 0; r < 4; ++r) {
                int m = w * 32 + mr * 16 + q * 4 + r;
                out[(size_t)(bm0 + m) * 132 + 4 + ct2 * 16 + r16] =
                    acc2[mr][ct2][r] + b2v;
            }
        }
    }
}

// ---------------------------------------------------------------------
extern "C" void kernel_launch(void* const* d_in, const int* in_sizes, int n_in,
                              void* d_out, int out_size, void* d_ws, size_t ws_size,
                              hipStream_t stream) {
    const float* z  = (const float*)d_in[0];
    const float* W1 = (const float*)d_in[1];
    const float* b1 = (const float*)d_in[2];
    const float* W2 = (const float*)d_in[3];
    const float* b2 = (const float*)d_in[4];
    float* out = (float*)d_out;

    // ws layout: [0, 512KB) W1^T bf16 swizzled, [512KB, 768KB) W2^T bf16
    uint4* w1t = (uint4*)d_ws;
    uint4* w2t = (uint4*)((char*)d_ws + 512 * 1024);

    hipLaunchKernelGGL(prep_weights, dim3(192), dim3(256), 0, stream,
                       W1, W2, w1t, w2t);
    hipLaunchKernelGGL(fused_all, dim3(512), dim3(256), 0, stream,
                       z, b1, b2, (const uint4*)w1t, (const uint4*)w2t, out);
}

// Round 3
// 75.440 us; speedup vs baseline: 1.5933x; 1.3362x over previous
//
#include <hip/hip_runtime.h>

// =====================================================================
// VeroneseDecoding: out[:, 0:4] = top-eigenvector(sym4x4(z[:, :10])) (sign-fixed)
//                   out[:, 4:132] = relu(z @ W1 + b1) @ W2 + b2
// Inputs (f32): z[65536,256], W1[256,1024], b1[1024], W2[1024,128], b2[128]
// Output (f32): [65536,132]
// =====================================================================

typedef short s16x8 __attribute__((ext_vector_type(8)));   // 8 bf16 (4 VGPRs)
typedef float f32x4 __attribute__((ext_vector_type(4)));
typedef unsigned char u8;

__device__ __forceinline__ f32x4 mfma16(s16x8 a, s16x8 b, f32x4 c) {
    return __builtin_amdgcn_mfma_f32_16x16x32_bf16(a, b, c, 0, 0, 0);
}

// manual RNE f32 -> bf16 bits (finite values only)
__device__ __forceinline__ short f2bf(float f) {
    unsigned int u = __float_as_uint(f);
    u = (u + 0x7fffu + ((u >> 16) & 1u)) >> 16;
    return (short)u;
}

// async global->LDS, 16B per lane. Dest must be wave-uniform base + lane*16.
__device__ __forceinline__ void gload_lds16(const void* g, void* l) {
    __builtin_amdgcn_global_load_lds(
        (const __attribute__((address_space(1))) unsigned int*)g,
        (__attribute__((address_space(3))) unsigned int*)l, 16, 0, 0);
}

// ---------------------------------------------------------------------
// prep: W1^T and W2^T -> bf16, XOR-swizzled in 16B units, into d_ws.
// w1t: [1024 n1][32 units]; unit (u ^ (n1&7)) holds W1[u*8 .. u*8+8)[n1]
// w2t: [ 128 n2][128 units]; unit (U ^ (n2&7)) holds W2[U*8 .. U*8+8)[n2]
// (swizzle flips only low 3 unit bits -> stays inside each 64-col k-slice,
//  so per-chunk staging is a plain linear copy)
// ---------------------------------------------------------------------
__global__ __launch_bounds__(256) void prep_weights(
    const float* __restrict__ W1, const float* __restrict__ W2,
    uint4* __restrict__ w1t, uint4* __restrict__ w2t)
{
    int tid = blockIdx.x * 256 + threadIdx.x;
    union { short b[8]; uint4 v; } pk;
    if (tid < 32768) {                 // 32 units * 1024 cols
        int u  = tid >> 10;            // k-unit 0..31
        int n1 = tid & 1023;
        #pragma unroll
        for (int j = 0; j < 8; ++j)
            pk.b[j] = f2bf(W1[(u * 8 + j) * 1024 + n1]);
        w1t[n1 * 32 + (u ^ (n1 & 7))] = pk.v;
    } else {                           // 128 units * 128 cols
        int id = tid - 32768;
        int U  = id >> 7;              // k-unit 0..127
        int n2 = id & 127;
        #pragma unroll
        for (int j = 0; j < 8; ++j)
            pk.b[j] = f2bf(W2[(U * 8 + j) * 128 + n2]);
        w2t[n2 * 128 + (U ^ (n2 & 7))] = pk.v;
    }
}

// ---------------------------------------------------------------------
// fused kernel: BM=256 rows/block, 512 threads = 8 waves x 32 rows, grid 256
// (1 block/CU). 16 chunks of 64 n1-cols, double-buffered weight staging
// (issue chunk c+1 before computing chunk c -> latency hidden under MFMA).
// LDS: bs1 2x32KB | bs2 2x16KB | h 8x4KB | bias 4KB = 132KB
// ---------------------------------------------------------------------
__global__ __launch_bounds__(512, 2) void fused_all(
    const float* __restrict__ z, const float* __restrict__ b1,
    const float* __restrict__ b2, const uint4* __restrict__ w1t,
    const uint4* __restrict__ w2t, float* __restrict__ out)
{
    __shared__ __align__(16) u8 lds[135168];
    u8* const bs1 = lds;                 // 2 x 32KB : [64 n1][512B]
    u8* const bs2 = lds + 65536;         // 2 x 16KB : [128 n2][128B]
    u8* const hsb = lds + 98304;         // 8 waves x 4KB : [32 m][128B]
    u8* const bls = lds + 131072;        // 4KB : b1 as f32

    const int t    = threadIdx.x;
    const int lane = t & 63;
    const int w    = t >> 6;        // wave 0..7
    const int q    = lane >> 4;     // 0..3
    const int r16  = lane & 15;
    const int bm0  = blockIdx.x * 256;
    const int rowbase = bm0 + w * 32;
    u8* const hw = hsb + w * 4096;  // wave-private h

    // ---------------- issue stage of chunk 0 + bias (async) ------------
    #pragma unroll
    for (int i = 0; i < 4; ++i) { int f = i * 512 + t; gload_lds16(w1t + f, bs1 + f * 16); }
    #pragma unroll
    for (int i = 0; i < 2; ++i) { int f = i * 512 + t; gload_lds16(w2t + (f >> 3) * 128 + (f & 7), bs2 + f * 16); }
    if (w < 4) gload_lds16(b1 + t * 4, bls + t * 16);

    // ---------------- eig (lanes 0..31: this wave's 32 rows) ------------
    if (lane < 32) {
        int row = rowbase + lane;
        const float* zr = z + (size_t)row * 256;
        float4 v0 = *(const float4*)(zr);
        float4 v1 = *(const float4*)(zr + 4);
        float2 v2 = *(const float2*)(zr + 8);

        float A[4][4] = {{v0.x, v0.y, v0.z, v0.w},
                         {v0.y, v1.x, v1.y, v1.z},
                         {v0.z, v1.y, v1.w, v2.x},
                         {v0.w, v1.z, v2.x, v2.y}};
        float V[4][4] = {{1.f, 0.f, 0.f, 0.f},
                         {0.f, 1.f, 0.f, 0.f},
                         {0.f, 0.f, 1.f, 0.f},
                         {0.f, 0.f, 0.f, 1.f}};

        // branchless Jacobi rotation (cndmask instead of divergent branch)
#define ROT(p, qq) do {                                                   \
        float apq  = A[p][qq];                                            \
        float tau  = (A[qq][qq] - A[p][p]) *                              \
                     __builtin_amdgcn_rcpf(2.0f * apq);                   \
        float tt   = __builtin_amdgcn_rcpf(                               \
                        fabsf(tau) +                                      \
                        __builtin_amdgcn_sqrtf(fmaf(tau, tau, 1.0f)));    \
        tt = copysignf(tt, tau);                                          \
        tt = (fabsf(apq) > 1e-20f) ? tt : 0.0f;                           \
        float cth = __builtin_amdgcn_rsqf(fmaf(tt, tt, 1.0f));            \
        float sth = tt * cth;                                             \
        _Pragma("unroll")                                                 \
        for (int k = 0; k < 4; ++k) {                                     \
            float akp = A[k][p], akq = A[k][qq];                          \
            A[k][p]  = cth * akp - sth * akq;                             \
            A[k][qq] = sth * akp + cth * akq;                             \
        }                                                                 \
        _Pragma("unroll")                                                 \
        for (int k = 0; k < 4; ++k) {                                     \
            float apk = A[p][k], aqk = A[qq][k];                          \
            A[p][k]  = cth * apk - sth * aqk;                             \
            A[qq][k] = sth * apk + cth * aqk;                             \
        }                                                                 \
        _Pragma("unroll")                                                 \
        for (int k = 0; k < 4; ++k) {                                     \
            float vkp = V[k][p], vkq = V[k][qq];                          \
            V[k][p]  = cth * vkp - sth * vkq;                             \
            V[k][qq] = sth * vkp + cth * vkq;                             \
        }                                                                 \
    } while (0)

        #pragma unroll 1
        for (int sweep = 0; sweep < 8; ++sweep) {
            ROT(0, 1); ROT(0, 2); ROT(0, 3); ROT(1, 2); ROT(1, 3); ROT(2, 3);
        }
#undef ROT

        float bv = A[0][0];
        float q0 = V[0][0], q1 = V[1][0], q2 = V[2][0], q3 = V[3][0];
        #pragma unroll
        for (int k = 1; k < 4; ++k) {
            bool better = A[k][k] > bv;
            bv = better ? A[k][k] : bv;
            q0 = better ? V[0][k] : q0;
            q1 = better ? V[1][k] : q1;
            q2 = better ? V[2][k] : q2;
            q3 = better ? V[3][k] : q3;
        }
        float sgn = (q0 + 1e-9f) >= 0.0f ? 1.0f : -1.0f;
        *(float4*)(out + (size_t)row * 132) =
            make_float4(sgn * q0, sgn * q1, sgn * q2, sgn * q3);
    }

    // ---------------- persistent z B-fragments --------------------------
    // zf[mr][s] = z[rowbase + mr*16 + r16][s*32 + q*8 .. +8)
    const f32x4 zero4 = {0.f, 0.f, 0.f, 0.f};
    s16x8 zf[2][8];
    #pragma unroll
    for (int mr = 0; mr < 2; ++mr) {
        const float* zp = z + (size_t)(rowbase + mr * 16 + r16) * 256;
        #pragma unroll
        for (int s = 0; s < 8; ++s) {
            const float4* p = (const float4*)(zp + s * 32 + q * 8);
            float4 a0 = p[0], a1 = p[1];
            s16x8 a;
            a[0] = f2bf(a0.x); a[1] = f2bf(a0.y); a[2] = f2bf(a0.z); a[3] = f2bf(a0.w);
            a[4] = f2bf(a1.x); a[5] = f2bf(a1.y); a[6] = f2bf(a1.z); a[7] = f2bf(a1.w);
            zf[mr][s] = a;
        }
    }

    f32x4 acc2[2][8];
    #pragma unroll
    for (int mr = 0; mr < 2; ++mr)
        #pragma unroll
        for (int n = 0; n < 8; ++n) acc2[mr][n] = zero4;

    __syncthreads();   // chunk-0 staging + bias landed

    // hoisted XOR-swizzle address components:
    //   (s*4+q)^(r16&7) decomposes: low2 = q^(e&3), bit2 = (s&1)^(e>>2)
    const int e      = r16 & 7;
    const int qx16   = (q ^ (e & 3)) << 4;
    const int e464   = (e & 4) << 4;                      // bit6 of offset
    const int base512 = r16 * 512 + qx16 + e464;          // bs1 rows (512B)
    const int base128 = r16 * 128 + qx16 + e464;          // bs2 / h rows (128B)
    const int e2     = (r16 >> 1) & 3;
    const int whb    = r16 * 128 + (((q >> 1) ^ (r16 & 1)) << 4) + (q & 1) * 8;

    auto chunk = [&](int c, int B1, int B2) {
        // ---- issue stage of chunk c+1 into the other buffer (T14) ----
        if (c < 15) {
            const uint4* s1 = w1t + (c + 1) * 2048;
            const int B1n = B1 ^ 32768, B2n = B2 ^ 16384;
            #pragma unroll
            for (int i = 0; i < 4; ++i) {
                int f = i * 512 + t;
                gload_lds16(s1 + f, bs1 + B1n + f * 16);
            }
            #pragma unroll
            for (int i = 0; i < 2; ++i) {
                int f = i * 512 + t;
                gload_lds16(w2t + (f >> 3) * 128 + (c + 1) * 8 + (f & 7),
                            bs2 + B2n + f * 16);
            }
        }

        const u8* a0p = bs1 + B1 + base512;          // s even
        const u8* a1p = bs1 + B1 + (base512 ^ 64);   // s odd
        const u8* bb  = bls + c * 256 + q * 16;      // bias (broadcast)

        // ---- GEMM1 (swapped): D[n1][m], n1 = ct*16+r16, m in zf frags ----
        #pragma unroll
        for (int ct = 0; ct < 4; ++ct) {
            f32x4 a0 = zero4, a1 = zero4;
            #pragma unroll
            for (int s = 0; s < 8; ++s) {
                const u8* ap = (s & 1) ? a1p : a0p;
                s16x8 afr = *(const s16x8*)(ap + ct * 8192 + (s >> 1) * 128);
                a0 = mfma16(afr, zf[0][s], a0);
                a1 = mfma16(afr, zf[1][s], a1);
            }
            f32x4 bv = *(const f32x4*)(bb + ct * 64);
            const int wo = whb + ((ct ^ e2) << 5);
            #pragma unroll
            for (int mr = 0; mr < 2; ++mr) {
                f32x4 av = mr ? a1 : a0;
                union { short h[4]; unsigned long long v; } pk;
                pk.h[0] = f2bf(fmaxf(av[0] + bv[0], 0.f));
                pk.h[1] = f2bf(fmaxf(av[1] + bv[1], 0.f));
                pk.h[2] = f2bf(fmaxf(av[2] + bv[2], 0.f));
                pk.h[3] = f2bf(fmaxf(av[3] + bv[3], 0.f));
                *(unsigned long long*)(hw + wo + mr * 2048) = pk.v;
            }
        }

        // ---- GEMM2 partial: acc2 += h_chunk @ W2_chunk (k2-range 64) ----
        // hw is wave-private (each wave reads only its own rows): no barrier
        #pragma unroll
        for (int s2 = 0; s2 < 2; ++s2) {
            const int boff = s2 ? (base128 ^ 64) : base128;
            const u8* hr = hw + boff;
            const u8* br = bs2 + B2 + boff;
            s16x8 af0 = *(const s16x8*)(hr);
            s16x8 af1 = *(const s16x8*)(hr + 2048);
            #pragma unroll
            for (int ct2 = 0; ct2 < 8; ++ct2) {
                s16x8 bfr = *(const s16x8*)(br + ct2 * 2048);
                acc2[0][ct2] = mfma16(af0, bfr, acc2[0][ct2]);
                acc2[1][ct2] = mfma16(af1, bfr, acc2[1][ct2]);
            }
        }

        __syncthreads();   // next-chunk staging landed; buffers safe to swap
    };

    #pragma unroll 1
    for (int cc = 0; cc < 8; ++cc) {
        chunk(2 * cc,     0,     0);
        chunk(2 * cc + 1, 32768, 16384);
    }

    // ---- epilogue: out[:, 4 + n2] = acc2 + b2 ----
    #pragma unroll
    for (int ct2 = 0; ct2 < 8; ++ct2) {
        const float b2v = b2[ct2 * 16 + r16];
        #pragma unroll
        for (int mr = 0; mr < 2; ++mr) {
            #pragma unroll
            for (int r = 0; r < 4; ++r) {
                int m = w * 32 + mr * 16 + q * 4 + r;
                out[(size_t)(bm0 + m) * 132 + 4 + ct2 * 16 + r16] =
                    acc2[mr][ct2][r] + b2v;
            }
        }
    }
}

// ---------------------------------------------------------------------
extern "C" void kernel_launch(void* const* d_in, const int* in_sizes, int n_in,
                              void* d_out, int out_size, void* d_ws, size_t ws_size,
                              hipStream_t stream) {
    const float* z  = (const float*)d_in[0];
    const float* W1 = (const float*)d_in[1];
    const float* b1 = (const float*)d_in[2];
    const float* W2 = (const float*)d_in[3];
    const float* b2 = (const float*)d_in[4];
    float* out = (float*)d_out;

    // ws layout: [0, 512KB) W1^T bf16 swizzled, [512KB, 768KB) W2^T bf16
    uint4* w1t = (uint4*)d_ws;
    uint4* w2t = (uint4*)((char*)d_ws + 512 * 1024);

    hipLaunchKernelGGL(prep_weights, dim3(192), dim3(256), 0, stream,
                       W1, W2, w1t, w2t);
    hipLaunchKernelGGL(fused_all, dim3(256), dim3(512), 0, stream,
                       z, b1, b2, (const uint4*)w1t, (const uint4*)w2t, out);
}

// Round 4
// 67.250 us; speedup vs baseline: 1.7873x; 1.1218x over previous
//
#include <hip/hip_runtime.h>

// =====================================================================
// VeroneseDecoding: out[:, 0:4] = top-eigenvector(sym4x4(z[:, :10])) (sign-fixed)
//                   out[:, 4:132] = relu(z @ W1 + b1) @ W2 + b2
// Inputs (f32): z[65536,256], W1[256,1024], b1[1024], W2[1024,128], b2[128]
// Output (f32): [65536,132]
// =====================================================================

typedef short s16x8 __attribute__((ext_vector_type(8)));   // 8 bf16 (4 VGPRs)
typedef float f32x4 __attribute__((ext_vector_type(4)));
typedef unsigned char u8;

__device__ __forceinline__ f32x4 mfma16(s16x8 a, s16x8 b, f32x4 c) {
    return __builtin_amdgcn_mfma_f32_16x16x32_bf16(a, b, c, 0, 0, 0);
}

// manual RNE f32 -> bf16 bits (prep kernel only; off critical path)
__device__ __forceinline__ short f2bf(float f) {
    unsigned int u = __float_as_uint(f);
    u = (u + 0x7fffu + ((u >> 16) & 1u)) >> 16;
    return (short)u;
}

// packed RNE convert: 2 f32 -> 1 dword of 2 bf16 (T12 recipe; no builtin)
__device__ __forceinline__ unsigned cvt_pk(float lo, float hi) {
    unsigned r;
    asm("v_cvt_pk_bf16_f32 %0, %1, %2" : "=v"(r) : "v"(lo), "v"(hi));
    return r;
}

// async global->LDS, 16B per lane. Dest must be wave-uniform base + lane*16.
__device__ __forceinline__ void gload_lds16(const void* g, void* l) {
    __builtin_amdgcn_global_load_lds(
        (const __attribute__((address_space(1))) unsigned int*)g,
        (__attribute__((address_space(3))) unsigned int*)l, 16, 0, 0);
}

// ---------------------------------------------------------------------
// prep: W1^T / W2^T -> bf16 in FRAGMENT-MAJOR order: each MFMA fragment's
// 64 lanes are 64 consecutive 16B units, so LDS staging is linear AND all
// ds_read_b128 are (uniform base + lane*16 + imm) -> conflict-free.
//   w1t unit f = ((c*4+ct)*8+s)*64 + q*16 + r16
//     holds W1[k = s*32+q*8+j][n1 = c*64+ct*16+r16], j=0..7
//   w2t unit f = ((c*2+s2)*8+ct2)*64 + q*16 + r16
//     holds W2[k2 = c*64+s2*32+q*8+j][n2 = ct2*16+r16]
// ---------------------------------------------------------------------
__global__ __launch_bounds__(256) void prep_weights(
    const float* __restrict__ W1, const float* __restrict__ W2,
    uint4* __restrict__ w1t, uint4* __restrict__ w2t)
{
    int tid = blockIdx.x * 256 + threadIdx.x;
    int q = (tid >> 4) & 3, r16 = tid & 15;
    union { short b[8]; uint4 v; } pk;
    if (tid < 32768) {                       // 32768 units = 512KB
        int s  = (tid >> 6) & 7;
        int ct = (tid >> 9) & 3;
        int c  = tid >> 11;
        int k0 = s * 32 + q * 8;
        int n1 = c * 64 + ct * 16 + r16;
        #pragma unroll
        for (int j = 0; j < 8; ++j)
            pk.b[j] = f2bf(W1[(k0 + j) * 1024 + n1]);
        w1t[tid] = pk.v;
    } else {                                 // 16384 units = 256KB
        int f   = tid - 32768;
        int ct2 = (f >> 6) & 7;
        int s2  = (f >> 9) & 1;
        int c   = f >> 10;
        int k0  = c * 64 + s2 * 32 + q * 8;
        int n2  = ct2 * 16 + r16;
        #pragma unroll
        for (int j = 0; j < 8; ++j)
            pk.b[j] = f2bf(W2[(k0 + j) * 128 + n2]);
        w2t[f] = pk.v;
    }
}

// ---------------------------------------------------------------------
// fused kernel: BM=256, 512 threads = 8 waves x 32 rows, grid 256
// (1 block/CU). 16 chunks of 64 n1-cols, double-buffered staging
// (issue c+1 before computing c). All LDS ops wave-linear.
// LDS: bs1 2x32KB | bs2 2x16KB | h 8x4KB | bias 4KB = 132KB
// ---------------------------------------------------------------------
__global__ __launch_bounds__(512, 2) void fused_all(
    const float* __restrict__ z, const float* __restrict__ b1,
    const float* __restrict__ b2, const uint4* __restrict__ w1t,
    const uint4* __restrict__ w2t, float* __restrict__ out)
{
    __shared__ __align__(16) u8 lds[135168];
    // [0,65536): bs1 (2 x 32KB)   [65536,98304): bs2 (2 x 16KB)
    // [98304,131072): h (8 waves x 4KB)   [131072,135168): b1 f32

    const int t    = threadIdx.x;
    const int lane = t & 63;
    const int w    = t >> 6;        // wave 0..7
    const int q    = lane >> 4;     // 0..3
    const int r16  = lane & 15;
    const int bm0  = blockIdx.x * 256;
    const int rowbase = bm0 + w * 32;

    // ---------------- issue stage of chunk 0 + bias (async) ------------
    #pragma unroll
    for (int i = 0; i < 4; ++i) {
        int f = i * 512 + t;
        gload_lds16(w1t + f, lds + f * 16);
    }
    #pragma unroll
    for (int i = 0; i < 2; ++i) {
        int f = i * 512 + t;
        gload_lds16(w2t + f, lds + 65536 + f * 16);
    }
    if (t < 256) gload_lds16(b1 + t * 4, lds + 131072 + t * 16);

    // ---------------- eig (lanes 0..31: this wave's 32 rows) ------------
    if (lane < 32) {
        int row = rowbase + lane;
        const float* zr = z + (size_t)row * 256;
        float4 v0 = *(const float4*)(zr);
        float4 v1 = *(const float4*)(zr + 4);
        float2 v2 = *(const float2*)(zr + 8);

        float A[4][4] = {{v0.x, v0.y, v0.z, v0.w},
                         {v0.y, v1.x, v1.y, v1.z},
                         {v0.z, v1.y, v1.w, v2.x},
                         {v0.w, v1.z, v2.x, v2.y}};
        float V[4][4] = {{1.f, 0.f, 0.f, 0.f},
                         {0.f, 1.f, 0.f, 0.f},
                         {0.f, 0.f, 1.f, 0.f},
                         {0.f, 0.f, 0.f, 1.f}};

#define ROT(p, qq) do {                                                   \
        float apq  = A[p][qq];                                            \
        float tau  = (A[qq][qq] - A[p][p]) *                              \
                     __builtin_amdgcn_rcpf(2.0f * apq);                   \
        float tt   = __builtin_amdgcn_rcpf(                               \
                        fabsf(tau) +                                      \
                        __builtin_amdgcn_sqrtf(fmaf(tau, tau, 1.0f)));    \
        tt = copysignf(tt, tau);                                          \
        tt = (fabsf(apq) > 1e-20f) ? tt : 0.0f;                           \
        float cth = __builtin_amdgcn_rsqf(fmaf(tt, tt, 1.0f));            \
        float sth = tt * cth;                                             \
        _Pragma("unroll")                                                 \
        for (int k = 0; k < 4; ++k) {                                     \
            float akp = A[k][p], akq = A[k][qq];                          \
            A[k][p]  = cth * akp - sth * akq;                             \
            A[k][qq] = sth * akp + cth * akq;                             \
        }                                                                 \
        _Pragma("unroll")                                                 \
        for (int k = 0; k < 4; ++k) {                                     \
            float apk = A[p][k], aqk = A[qq][k];                          \
            A[p][k]  = cth * apk - sth * aqk;                             \
            A[qq][k] = sth * apk + cth * aqk;                             \
        }                                                                 \
        _Pragma("unroll")                                                 \
        for (int k = 0; k < 4; ++k) {                                     \
            float vkp = V[k][p], vkq = V[k][qq];                          \
            V[k][p]  = cth * vkp - sth * vkq;                             \
            V[k][qq] = sth * vkp + cth * vkq;                             \
        }                                                                 \
    } while (0)

        #pragma unroll 1
        for (int sweep = 0; sweep < 6; ++sweep) {
            ROT(0, 1); ROT(0, 2); ROT(0, 3); ROT(1, 2); ROT(1, 3); ROT(2, 3);
        }
#undef ROT

        float bv = A[0][0];
        float q0 = V[0][0], q1 = V[1][0], q2 = V[2][0], q3 = V[3][0];
        #pragma unroll
        for (int k = 1; k < 4; ++k) {
            bool better = A[k][k] > bv;
            bv = better ? A[k][k] : bv;
            q0 = better ? V[0][k] : q0;
            q1 = better ? V[1][k] : q1;
            q2 = better ? V[2][k] : q2;
            q3 = better ? V[3][k] : q3;
        }
        float sgn = (q0 + 1e-9f) >= 0.0f ? 1.0f : -1.0f;
        *(float4*)(out + (size_t)row * 132) =
            make_float4(sgn * q0, sgn * q1, sgn * q2, sgn * q3);
    }

    // ---------------- persistent z B-fragments (cvt_pk packed) ----------
    // zf[mr][s] = z[rowbase + mr*16 + r16][s*32 + q*8 .. +8)
    const f32x4 zero4 = {0.f, 0.f, 0.f, 0.f};
    s16x8 zf[2][8];
    #pragma unroll
    for (int mr = 0; mr < 2; ++mr) {
        const float* zp = z + (size_t)(rowbase + mr * 16 + r16) * 256 + q * 8;
        #pragma unroll
        for (int s = 0; s < 8; ++s) {
            const float4* p = (const float4*)(zp + s * 32);
            float4 a0 = p[0], a1 = p[1];
            union { unsigned u[4]; s16x8 v; } pk;
            pk.u[0] = cvt_pk(a0.x, a0.y);
            pk.u[1] = cvt_pk(a0.z, a0.w);
            pk.u[2] = cvt_pk(a1.x, a1.y);
            pk.u[3] = cvt_pk(a1.z, a1.w);
            zf[mr][s] = pk.v;
        }
    }

    f32x4 acc2[2][8];
    #pragma unroll
    for (int mr = 0; mr < 2; ++mr)
        #pragma unroll
        for (int n = 0; n < 8; ++n) acc2[mr][n] = zero4;

    __syncthreads();   // chunk-0 staging + bias landed

    // thread-constant LDS base pointers (all inner accesses = base + imm)
    const u8* const aW0 = lds + lane * 16;            // bs1 buf0
    const u8* const aW1 = lds + 32768 + lane * 16;    // bs1 buf1
    const u8* const bW0 = lds + 65536 + lane * 16;    // bs2 buf0
    const u8* const bW1 = lds + 81920 + lane * 16;    // bs2 buf1
    u8* const hwv       = lds + 98304 + w * 4096;
    const u8* const hr  = hwv + lane * 16;                          // h read
    u8* const hwr = hwv + r16 * 16 + (q >> 1) * 256 + (q & 1) * 8;  // h write
    const u8* const blsp = lds + 131072 + q * 16;

    auto chunk = [&](int c, const u8* a, const u8* bW,
                     u8* s1dst, u8* s2dst) {
        // ---- issue stage of chunk c+1 into the other buffer ----
        if (c < 15) {
            const uint4* s1 = w1t + (c + 1) * 2048;
            const uint4* s2 = w2t + (c + 1) * 1024;
            #pragma unroll
            for (int i = 0; i < 4; ++i) {
                int f = i * 512 + t;
                gload_lds16(s1 + f, s1dst + f * 16);
            }
            #pragma unroll
            for (int i = 0; i < 2; ++i) {
                int f = i * 512 + t;
                gload_lds16(s2 + f, s2dst + f * 16);
            }
        }

        // ---- GEMM1 (swapped): D[n1][m]; h-pack via cvt_pk; b64 write ----
        #pragma unroll
        for (int ct = 0; ct < 4; ++ct) {
            f32x4 a0 = zero4, a1 = zero4;
            #pragma unroll
            for (int s = 0; s < 8; ++s) {
                s16x8 afr = *(const s16x8*)(a + (ct * 8 + s) * 1024);
                a0 = mfma16(afr, zf[0][s], a0);
                a1 = mfma16(afr, zf[1][s], a1);
            }
            f32x4 bv = *(const f32x4*)(blsp + c * 256 + ct * 64);
            #pragma unroll
            for (int mr = 0; mr < 2; ++mr) {
                f32x4 av = mr ? a1 : a0;
                uint2 hp;
                hp.x = cvt_pk(fmaxf(av[0] + bv[0], 0.f),
                              fmaxf(av[1] + bv[1], 0.f));
                hp.y = cvt_pk(fmaxf(av[2] + bv[2], 0.f),
                              fmaxf(av[3] + bv[3], 0.f));
                *(uint2*)(hwr + mr * 2048 + ct * 512) = hp;
            }
        }

        // ---- GEMM2 partial (h wave-private: no barrier) ----
        #pragma unroll
        for (int s2 = 0; s2 < 2; ++s2) {
            s16x8 af0 = *(const s16x8*)(hr + s2 * 1024);
            s16x8 af1 = *(const s16x8*)(hr + 2048 + s2 * 1024);
            #pragma unroll
            for (int ct2 = 0; ct2 < 8; ++ct2) {
                s16x8 bfr = *(const s16x8*)(bW + (s2 * 8 + ct2) * 1024);
                acc2[0][ct2] = mfma16(af0, bfr, acc2[0][ct2]);
                acc2[1][ct2] = mfma16(af1, bfr, acc2[1][ct2]);
            }
        }

        __syncthreads();   // next-chunk staging landed; buffers swap
    };

    u8* const s1b0 = lds;
    u8* const s1b1 = lds + 32768;
    u8* const s2b0 = lds + 65536;
    u8* const s2b1 = lds + 81920;

    #pragma unroll 1
    for (int cc = 0; cc < 8; ++cc) {
        chunk(2 * cc,     aW0, bW0, s1b1, s2b1);
        chunk(2 * cc + 1, aW1, bW1, s1b0, s2b0);
    }

    // ---- epilogue: out[:, 4 + n2] = acc2 + b2 ----
    #pragma unroll
    for (int ct2 = 0; ct2 < 8; ++ct2) {
        const float b2v = b2[ct2 * 16 + r16];
        #pragma unroll
        for (int mr = 0; mr < 2; ++mr) {
            #pragma unroll
            for (int r = 0; r < 4; ++r) {
                int m = w * 32 + mr * 16 + q * 4 + r;
                out[(size_t)(bm0 + m) * 132 + 4 + ct2 * 16 + r16] =
                    acc2[mr][ct2][r] + b2v;
            }
        }
    }
}

// ---------------------------------------------------------------------
extern "C" void kernel_launch(void* const* d_in, const int* in_sizes, int n_in,
                              void* d_out, int out_size, void* d_ws, size_t ws_size,
                              hipStream_t stream) {
    const float* z  = (const float*)d_in[0];
    const float* W1 = (const float*)d_in[1];
    const float* b1 = (const float*)d_in[2];
    const float* W2 = (const float*)d_in[3];
    const float* b2 = (const float*)d_in[4];
    float* out = (float*)d_out;

    // ws layout: [0, 512KB) W1^T frag-major, [512KB, 768KB) W2^T frag-major
    uint4* w1t = (uint4*)d_ws;
    uint4* w2t = (uint4*)((char*)d_ws + 512 * 1024);

    hipLaunchKernelGGL(prep_weights, dim3(192), dim3(256), 0, stream,
                       W1, W2, w1t, w2t);
    hipLaunchKernelGGL(fused_all, dim3(256), dim3(512), 0, stream,
                       z, b1, b2, (const uint4*)w1t, (const uint4*)w2t, out);
}